// Round 1
// baseline (412.385 us; speedup 1.0000x reference)
//
#include <hip/hip_runtime.h>

// DYDConv2d: dynamic per-pixel depthwise 3x3 conv, stride 1, pad 1.
// input  [B=8, C=64, H=128, W=128] fp32
// weight [B, C, 3, 3, outH=128, outW=128] fp32   (302 MB, single-use)
// output [B, C, 128, 128] fp32
//
// Memory-bound: min traffic ~336 MB -> ~51-53 us at achieved 6.3-6.6 TB/s.
// Measured 399 us wall = ~282 us harness resets (1.2 GB poison @182 us
// measured + input restore) + kernel (<181 us, absent from top-5).
// R4 probe: 8 output cols/thread (was 4). Halves wave count, doubles
// per-thread bytes-in-flight, halves shuffle/addr overhead per byte.
// Traffic identical; coalescing identical (all loads full cache lines).
// If BW-floor already: no change -> declare roofline next round.

typedef float vfloat4 __attribute__((ext_vector_type(4)));

namespace {
constexpr int kH = 128;
constexpr int kW = 128;
constexpr int kPlane = kH * kW;                        // 16384
constexpr int kThreadsTotal = 8 * 64 * kH * (kW / 8);  // 1,048,576
}

__global__ __launch_bounds__(256) void dyd_conv_kernel(
    const float* __restrict__ in,
    const float* __restrict__ wgt,
    float* __restrict__ out) {
    int idx = blockIdx.x * blockDim.x + threadIdx.x;
    int lane = threadIdx.x & 63;
    // lane layout: 16 threads per output row (8 cols each), 4 rows per wave.
    // Every vector op is a fully-coalesced wave transaction (128B-line
    // aligned 256B chunks per row).
    int ow0 = (idx & 15) << 3;        // 0,8,...,120 (16B-aligned)
    int oh  = (idx >> 4) & 127;
    int bc  = idx >> 11;              // b*C + c

    const float* inp = in + (size_t)bc * kPlane;
    const float* wp  = wgt + (size_t)bc * (9 * kPlane) + oh * kW + ow0;

    float acc0 = 0.f, acc1 = 0.f, acc2 = 0.f, acc3 = 0.f;
    float acc4 = 0.f, acc5 = 0.f, acc6 = 0.f, acc7 = 0.f;

#pragma unroll
    for (int i = 0; i < 3; ++i) {
        int ih = oh + i - 1;
        vfloat4 A = {0.f, 0.f, 0.f, 0.f};   // cols ow0..ow0+3
        vfloat4 B = {0.f, 0.f, 0.f, 0.f};   // cols ow0+4..ow0+7
        if (ih >= 0 && ih < kH) {
            A = *(const vfloat4*)(inp + ih * kW + ow0);
            B = *(const vfloat4*)(inp + ih * kW + ow0 + 4);
        }

        // Halo columns from neighbor lanes. Lanes whose pull crosses a row
        // edge are exactly the pad lanes -> masked to 0.
        float c0 = __shfl(B.w, lane - 1);   // col ow0-1
        float c9 = __shfl(A.x, lane + 1);   // col ow0+8
        if (ow0 == 0)        c0 = 0.f;
        if (ow0 + 8 >= kW)   c9 = 0.f;

        // Single-use weights: nontemporal to avoid polluting L2.
        vfloat4 w0a = __builtin_nontemporal_load((const vfloat4*)(wp + (i * 3 + 0) * kPlane));
        vfloat4 w0b = __builtin_nontemporal_load((const vfloat4*)(wp + (i * 3 + 0) * kPlane + 4));
        vfloat4 w1a = __builtin_nontemporal_load((const vfloat4*)(wp + (i * 3 + 1) * kPlane));
        vfloat4 w1b = __builtin_nontemporal_load((const vfloat4*)(wp + (i * 3 + 1) * kPlane + 4));
        vfloat4 w2a = __builtin_nontemporal_load((const vfloat4*)(wp + (i * 3 + 2) * kPlane));
        vfloat4 w2b = __builtin_nontemporal_load((const vfloat4*)(wp + (i * 3 + 2) * kPlane + 4));

        // m[t] = input col ow0 + t - 1
        float m0 = c0,  m1 = A.x, m2 = A.y, m3 = A.z, m4 = A.w;
        float m5 = B.x, m6 = B.y, m7 = B.z, m8 = B.w, m9 = c9;

        acc0 += w0a.x * m0 + w1a.x * m1 + w2a.x * m2;
        acc1 += w0a.y * m1 + w1a.y * m2 + w2a.y * m3;
        acc2 += w0a.z * m2 + w1a.z * m3 + w2a.z * m4;
        acc3 += w0a.w * m3 + w1a.w * m4 + w2a.w * m5;
        acc4 += w0b.x * m4 + w1b.x * m5 + w2b.x * m6;
        acc5 += w0b.y * m5 + w1b.y * m6 + w2b.y * m7;
        acc6 += w0b.z * m6 + w1b.z * m7 + w2b.z * m8;
        acc7 += w0b.w * m7 + w1b.w * m8 + w2b.w * m9;
    }

    float* op = out + (size_t)bc * kPlane + oh * kW + ow0;
    vfloat4 oA = {acc0, acc1, acc2, acc3};
    vfloat4 oB = {acc4, acc5, acc6, acc7};
    __builtin_nontemporal_store(oA, (vfloat4*)op);
    __builtin_nontemporal_store(oB, (vfloat4*)(op + 4));
}

extern "C" void kernel_launch(void* const* d_in, const int* in_sizes, int n_in,
                              void* d_out, int out_size, void* d_ws, size_t ws_size,
                              hipStream_t stream) {
    const float* in  = (const float*)d_in[0];
    const float* wgt = (const float*)d_in[1];
    float* out = (float*)d_out;
    constexpr int kBlock = 256;
    constexpr int kGrid = kThreadsTotal / kBlock;   // 4096
    dyd_conv_kernel<<<kGrid, kBlock, 0, stream>>>(in, wgt, out);
}

// Round 3
// 398.763 us; speedup vs baseline: 1.0342x; 1.0342x over previous
//
#include <hip/hip_runtime.h>

// DYDConv2d: dynamic per-pixel depthwise 3x3 conv, stride 1, pad 1.
// input  [B=8, C=64, H=128, W=128] fp32
// weight [B, C, 3, 3, outH=128, outW=128] fp32   (302 MB, single-use)
// output [B, C, 128, 128] fp32
//
// Memory-bound: min traffic ~336 MB -> ~51-53 us at achieved 6.3-6.6 TB/s.
// Wall 399 us = ~282 us harness resets (1.2 GB poison @182 us measured +
// input restore) + kernel (<181 us, absent from rocprof top-5).
// R4 post-mortem: 8 cols/thread was SLOWER (+13 us) despite fewer
// instructions -> half-dense strided weight loads doubled cache-line
// transactions. Keep the wave-dense 4-col layout (every load = one fully
// used 1 KB wave transaction).
// R5 probe (rerun; R2 bench was an infra failure): branchless clamped
// input-row loads (zero via cndmask instead of exec-mask branch) so all
// 12 loads per thread cluster and issue early.
// If flat at ~399 -> kernel is at BW floor; declare roofline.

typedef float vfloat4 __attribute__((ext_vector_type(4)));

namespace {
constexpr int kH = 128;
constexpr int kW = 128;
constexpr int kPlane = kH * kW;                          // 16384
constexpr int kThreadsTotal = 8 * 64 * kH * (kW / 4);    // 2,097,152
}

__global__ __launch_bounds__(256) void dyd_conv_kernel(
    const float* __restrict__ in,
    const float* __restrict__ wgt,
    float* __restrict__ out) {
    int idx = blockIdx.x * blockDim.x + threadIdx.x;
    int lane = threadIdx.x & 63;
    // lane layout: 32 threads per output row (4 cols each), rows contiguous,
    // so every vector op is a fully-coalesced 1 KB wave transaction.
    int ow0 = (idx & 31) << 2;        // 0,4,...,124 (16B-aligned)
    int oh  = (idx >> 5) & 127;
    int bc  = idx >> 12;              // b*C + c

    const float* inp = in + (size_t)bc * kPlane;
    const float* wp  = wgt + (size_t)bc * (9 * kPlane) + oh * kW + ow0;

    float acc0 = 0.f, acc1 = 0.f, acc2 = 0.f, acc3 = 0.f;

#pragma unroll
    for (int i = 0; i < 3; ++i) {
        int ih = oh + i - 1;
        // Branchless: clamp row address (always in-bounds), zero via select.
        // No exec-mask diamond -> compiler can hoist/cluster all loads.
        int ihc = ih < 0 ? 0 : (ih > kH - 1 ? kH - 1 : ih);
        bool valid = (unsigned)ih < (unsigned)kH;
        vfloat4 mid = *(const vfloat4*)(inp + ihc * kW + ow0);
        mid = valid ? mid : (vfloat4){0.f, 0.f, 0.f, 0.f};

        // Halo columns from neighbor lanes. Lanes whose pull crosses a row
        // edge are exactly the pad lanes -> masked to 0.
        float c0 = __shfl(mid.w, lane - 1);   // col ow0-1
        float c5 = __shfl(mid.x, lane + 1);   // col ow0+4
        if (ow0 == 0)        c0 = 0.f;
        if (ow0 + 4 >= kW)   c5 = 0.f;

        // Single-use weights: nontemporal to avoid polluting L2.
        vfloat4 w0 = __builtin_nontemporal_load((const vfloat4*)(wp + (i * 3 + 0) * kPlane));
        vfloat4 w1 = __builtin_nontemporal_load((const vfloat4*)(wp + (i * 3 + 1) * kPlane));
        vfloat4 w2 = __builtin_nontemporal_load((const vfloat4*)(wp + (i * 3 + 2) * kPlane));

        acc0 += w0.x * c0    + w1.x * mid.x + w2.x * mid.y;
        acc1 += w0.y * mid.x + w1.y * mid.y + w2.y * mid.z;
        acc2 += w0.z * mid.y + w1.z * mid.z + w2.z * mid.w;
        acc3 += w0.w * mid.z + w1.w * mid.w + w2.w * c5;
    }

    vfloat4 o = {acc0, acc1, acc2, acc3};
    __builtin_nontemporal_store(o, (vfloat4*)(out + (size_t)bc * kPlane + oh * kW + ow0));
}

extern "C" void kernel_launch(void* const* d_in, const int* in_sizes, int n_in,
                              void* d_out, int out_size, void* d_ws, size_t ws_size,
                              hipStream_t stream) {
    const float* in  = (const float*)d_in[0];
    const float* wgt = (const float*)d_in[1];
    float* out = (float*)d_out;
    constexpr int kBlock = 256;
    constexpr int kGrid = kThreadsTotal / kBlock;   // 8192
    dyd_conv_kernel<<<kGrid, kBlock, 0, stream>>>(in, wgt, out);
}